// Round 2
// baseline (1194.008 us; speedup 1.0000x reference)
//
#include <hip/hip_runtime.h>
#include <hip/hip_bf16.h>
#include <math.h>

#define B_ 8
#define L_ 2048
#define E_ 100
#define F_ 256
#define KW 9
#define Y_ 8921
#define YP 8960      // Y padded to 70*128
#define KC 928       // conv K padded: 9*100=900 -> 928 (29 K-steps of 32)
#define MC 16384     // B*L

#define VMCNT(n) asm volatile("s_waitcnt vmcnt(" #n ")" ::: "memory")
#define CFENCE() asm volatile("" ::: "memory")

typedef __bf16 bf16x8 __attribute__((ext_vector_type(8)));
typedef float f32x4 __attribute__((ext_vector_type(4)));

__device__ __forceinline__ unsigned short f2bf(float v) {
  __hip_bfloat16 h = __float2bfloat16(v);
  return *reinterpret_cast<unsigned short*>(&h);
}

__device__ __forceinline__ void gld_lds16(const unsigned short* g, unsigned short* l) {
  __builtin_amdgcn_global_load_lds((const __attribute__((address_space(1))) void*)g,
                                   (__attribute__((address_space(3))) void*)l,
                                   16, 0, 0);
}

// Stage a 128x32 bf16 tile into LDS [128][32] (linear dest), with XOR swizzle
// applied on the GLOBAL source (rule #21: linear dest + inv-swz source + swz read).
// slot s (16B unit within 64B row) holds global slot s ^ ((row>>1)&3).
template <int STRIDE, int NT>
__device__ __forceinline__ void stage_tile(const unsigned short* __restrict__ g,
                                           unsigned short* __restrict__ lds, int tid) {
#pragma unroll
  for (int r = 0; r < 512 / NT; ++r) {
    int c = r * NT + tid;
    int row = c >> 2, s = c & 3;
    gld_lds16(g + (size_t)row * STRIDE + ((s ^ ((row >> 1) & 3)) * 8), lds + c * 8);
  }
}

// ---------------- im2col: [B*L, 928] bf16, direct from embedding gather ------
__global__ __launch_bounds__(256) void im2col_kernel(const int* __restrict__ x,
                                                     const float* __restrict__ embedW,
                                                     unsigned short* __restrict__ im) {
  int idx = blockIdx.x * 256 + threadIdx.x;  // < 16384*232
  if (idx >= MC * (KC / 4)) return;
  int row = idx / (KC / 4), g4 = idx - row * (KC / 4);
  int kk = g4 * 4;
  ushort4 o = {0, 0, 0, 0};
  if (kk < 900) {
    int k = kk / 100, e = kk - k * 100;
    int b = row >> 11, l = row & 2047;
    int ls = l + k - 4;
    if (ls >= 0 && ls < L_) {
      const float4 v = *reinterpret_cast<const float4*>(
          &embedW[(size_t)x[b * L_ + ls] * E_ + e]);
      o.x = f2bf(v.x); o.y = f2bf(v.y); o.z = f2bf(v.z); o.w = f2bf(v.w);
    }
  }
  *reinterpret_cast<ushort4*>(&im[(size_t)idx * 4]) = o;
}

// ---------------- pack conv_w [F,E,K] -> wconv [F][k*100+e] bf16 -------------
__global__ __launch_bounds__(256) void wpack_kernel(const float* __restrict__ convw,
                                                    unsigned short* __restrict__ wc) {
  int idx = blockIdx.x * 256 + threadIdx.x;
  if (idx >= F_ * KC) return;
  int f = idx / KC, kk = idx - f * KC;
  float v = 0.f;
  if (kk < 900) {
    int k = kk / 100, e = kk - k * 100;
    v = convw[f * 900 + e * 9 + k];
  }
  wc[idx] = f2bf(v);
}

// ---------------- pack U_w / final_w to bf16, padded to 8960 rows ------------
__global__ __launch_bounds__(256) void ufpack_kernel(const float* __restrict__ Uw,
                                                     const float* __restrict__ Fww,
                                                     unsigned short* __restrict__ Ub,
                                                     unsigned short* __restrict__ Fwb) {
  int idx = blockIdx.x * 256 + threadIdx.x;
  if (idx >= 2 * YP * F_) return;
  int sel = idx / (YP * F_);
  int r = idx - sel * (YP * F_);
  int y = r / F_, f = r - y * F_;
  float v = (y < Y_) ? (sel ? Fww[y * F_ + f] : Uw[y * F_ + f]) : 0.f;
  (sel ? Fwb : Ub)[r] = f2bf(v);
}

// ---------------- conv GEMM: h[m,n] = tanh(im2col * wconv^T + b) -------------
__global__ __launch_bounds__(256) void conv_gemm(const unsigned short* __restrict__ A,
                                                 const unsigned short* __restrict__ Bt,
                                                 const float* __restrict__ convb,
                                                 unsigned short* __restrict__ hb) {
  __shared__ unsigned short As[3][128 * 32], Bs[3][128 * 32];
  const int mt = blockIdx.x, nt = blockIdx.y, tid = threadIdx.x;
  const unsigned short* Ag = A + (size_t)mt * 128 * KC;
  const unsigned short* Bg = Bt + (size_t)nt * 128 * KC;
  f32x4 acc[4][4] = {};
  const int lane = tid & 63, wv = tid >> 6;
  const int wy = wv >> 1, wx = wv & 1, lr = lane & 15, lq = lane >> 4;
  const int bOff = (lq ^ ((lr >> 1) & 3)) * 8;  // swizzled 16B-slot within 64B row
  stage_tile<KC, 256>(Ag, As[0], tid);
  stage_tile<KC, 256>(Bg, Bs[0], tid);
  for (int kt = 0; kt < 29; ++kt) {
    const int cur = kt % 3;
    if (kt + 1 < 29) {
      const int nxt = (kt + 1) % 3;
      stage_tile<KC, 256>(Ag + (kt + 1) * 32, As[nxt], tid);
      stage_tile<KC, 256>(Bg + (kt + 1) * 32, Bs[nxt], tid);
      VMCNT(4);
    } else {
      VMCNT(0);
    }
    __builtin_amdgcn_s_barrier();
    CFENCE();
    bf16x8 a[4], bb[4];
#pragma unroll
    for (int i = 0; i < 4; ++i) a[i] = *(const bf16x8*)&As[cur][(wy * 64 + i * 16 + lr) * 32 + bOff];
#pragma unroll
    for (int j = 0; j < 4; ++j) bb[j] = *(const bf16x8*)&Bs[cur][(wx * 64 + j * 16 + lr) * 32 + bOff];
#pragma unroll
    for (int i = 0; i < 4; ++i)
#pragma unroll
      for (int j = 0; j < 4; ++j)
        acc[i][j] = __builtin_amdgcn_mfma_f32_16x16x32_bf16(a[i], bb[j], acc[i][j], 0, 0, 0);
  }
#pragma unroll
  for (int j = 0; j < 4; ++j) {
    const int n = nt * 128 + wx * 64 + j * 16 + lr;
    const float cb = convb[n];
#pragma unroll
    for (int i = 0; i < 4; ++i)
#pragma unroll
      for (int r = 0; r < 4; ++r) {
        const int m = mt * 128 + wy * 64 + i * 16 + lq * 4 + r;
        hb[(size_t)m * F_ + n] = f2bf(tanhf(acc[i][j][r] + cb));
      }
  }
}

// -------- fused attention: per (yt,b): scores+rowsum, then alpha+yhat --------
// 512 threads = 8 waves (2y x 4x). U,Fw LDS-resident [128][256] (XOR-swz slot^row&7).
// hb B-tiles [128][32] triple-buffered, counted vmcnt(1), 1 barrier/K-step.
__global__ __launch_bounds__(512, 1) void attn_fused(const unsigned short* __restrict__ U,
                                                     const unsigned short* __restrict__ Fw,
                                                     const unsigned short* __restrict__ hb,
                                                     const float* __restrict__ Fb,
                                                     float* __restrict__ alpha,
                                                     float* __restrict__ yhat) {
  __shared__ unsigned short Us[128 * 256];   // 64 KB
  __shared__ unsigned short Fws[128 * 256];  // 64 KB
  __shared__ unsigned short Bs[3][128 * 32]; // 24 KB
  const int yt = blockIdx.x, b = blockIdx.y, tid = threadIdx.x;
  const int lane = tid & 63, wv = tid >> 6;
  const int wy = wv >> 2, wx = wv & 3, lr = lane & 15, lq = lane >> 4;
  const unsigned short* Ug = U + (size_t)yt * 128 * F_;
  const unsigned short* Fg = Fw + (size_t)yt * 128 * F_;
  const unsigned short* Hg = hb + (size_t)b * L_ * F_;

  // ---- stage U resident (4096 chunks / 512 thr = 8 rounds), swz slot^ (row&7)
#pragma unroll
  for (int r = 0; r < 8; ++r) {
    int c = r * 512 + tid;
    int row = c >> 5, s = c & 31;
    gld_lds16(Ug + row * F_ + ((s ^ (row & 7)) * 8), Us + c * 8);
  }
  // stage first B tile (lt=0, kt=0)
  {
    int c = tid, row = c >> 2, s = c & 3;
    gld_lds16(Hg + (size_t)row * F_ + ((s ^ ((row >> 1) & 3)) * 8), Bs[0] + c * 8);
  }
  VMCNT(0);
  __builtin_amdgcn_s_barrier();
  CFENCE();

  const int bOff = (lq ^ ((lr >> 1) & 3)) * 8;   // B-tile slot swizzle (row-dep part = (lr>>1)&3)
  const int lr7 = lr & 7;                        // U-tile swizzle row-dep part

  // ================= pass 1: scores, accumulate exp row-sums =================
  float rsA[4][4] = {};
  f32x4 acc[4][2];
  for (int t = 0; t < 128; ++t) {
    const int kt = t & 7;
    if (t + 1 < 128) {
      const int c = tid, row = c >> 2, s = c & 3;
      const int lt1 = (t + 1) >> 3, kt1 = (t + 1) & 7;
      gld_lds16(Hg + (size_t)(lt1 * 128 + row) * F_ + kt1 * 32 + ((s ^ ((row >> 1) & 3)) * 8),
                Bs[(t + 1) % 3] + c * 8);
      VMCNT(1);
    } else {
      VMCNT(0);
    }
    __builtin_amdgcn_s_barrier();
    CFENCE();
    if (kt == 0) {
#pragma unroll
      for (int i = 0; i < 4; ++i)
#pragma unroll
        for (int j = 0; j < 2; ++j) acc[i][j] = (f32x4){0.f, 0.f, 0.f, 0.f};
    }
    const unsigned short* bs = Bs[t % 3];
    const int colOff = (((kt * 4 + lq) ^ lr7)) * 8;
    bf16x8 a[4], bbf[2];
#pragma unroll
    for (int i = 0; i < 4; ++i) a[i] = *(const bf16x8*)&Us[(wy * 64 + i * 16 + lr) * 256 + colOff];
#pragma unroll
    for (int j = 0; j < 2; ++j) bbf[j] = *(const bf16x8*)&bs[(wx * 32 + j * 16 + lr) * 32 + bOff];
#pragma unroll
    for (int i = 0; i < 4; ++i)
#pragma unroll
      for (int j = 0; j < 2; ++j)
        acc[i][j] = __builtin_amdgcn_mfma_f32_16x16x32_bf16(a[i], bbf[j], acc[i][j], 0, 0, 0);
    if (kt == 7) {
#pragma unroll
      for (int i = 0; i < 4; ++i)
#pragma unroll
        for (int r = 0; r < 4; ++r) {
          float rs = __expf(acc[i][0][r]) + __expf(acc[i][1][r]);
#pragma unroll
          for (int off = 1; off < 16; off <<= 1) rs += __shfl_xor(rs, off);
          rsA[i][r] += rs;
        }
    }
  }

  // ---- stage Fw resident (overlap with rowsum combine) ----
#pragma unroll
  for (int r = 0; r < 8; ++r) {
    int c = r * 512 + tid;
    int row = c >> 5, s = c & 31;
    gld_lds16(Fg + row * F_ + ((s ^ (row & 7)) * 8), Fws + c * 8);
  }
  __syncthreads();  // Bs reads done; Fw loads drained (vmcnt0 in syncthreads)
  // ---- combine row sums across wx, compute per-thread sinv ----
  float* red = (float*)Bs;  // 128*4 floats (reuse Bs)
#pragma unroll
  for (int i = 0; i < 4; ++i)
#pragma unroll
    for (int r = 0; r < 4; ++r)
      if (lr == 0) red[(wy * 64 + i * 16 + lq * 4 + r) * 4 + wx] = rsA[i][r];
  __syncthreads();
  float si[4][4];
#pragma unroll
  for (int i = 0; i < 4; ++i)
#pragma unroll
    for (int r = 0; r < 4; ++r) {
      const int row = wy * 64 + i * 16 + lq * 4 + r;
      si[i][r] = 1.f / (red[row * 4] + red[row * 4 + 1] + red[row * 4 + 2] + red[row * 4 + 3]);
    }
  __syncthreads();  // si reads done before Bs is restaged

  // ================= pass 2: alpha + yhat numerator ==========================
  {
    int c = tid, row = c >> 2, s = c & 3;
    gld_lds16(Hg + (size_t)row * F_ + ((s ^ ((row >> 1) & 3)) * 8), Bs[0] + c * 8);
  }
  VMCNT(0);
  __builtin_amdgcn_s_barrier();
  CFENCE();
  float nsA[4][4] = {};
  f32x4 accs[4][2], accg[4][2];
  for (int t = 0; t < 128; ++t) {
    const int kt = t & 7, lt = t >> 3;
    if (t + 1 < 128) {
      const int c = tid, row = c >> 2, s = c & 3;
      const int lt1 = (t + 1) >> 3, kt1 = (t + 1) & 7;
      gld_lds16(Hg + (size_t)(lt1 * 128 + row) * F_ + kt1 * 32 + ((s ^ ((row >> 1) & 3)) * 8),
                Bs[(t + 1) % 3] + c * 8);
      VMCNT(1);
    } else {
      VMCNT(0);
    }
    __builtin_amdgcn_s_barrier();
    CFENCE();
    if (kt == 0) {
#pragma unroll
      for (int i = 0; i < 4; ++i)
#pragma unroll
        for (int j = 0; j < 2; ++j) {
          accs[i][j] = (f32x4){0.f, 0.f, 0.f, 0.f};
          accg[i][j] = (f32x4){0.f, 0.f, 0.f, 0.f};
        }
    }
    const unsigned short* bs = Bs[t % 3];
    const int colOff = (((kt * 4 + lq) ^ lr7)) * 8;
    bf16x8 a1[4], a2[4], bbf[2];
#pragma unroll
    for (int i = 0; i < 4; ++i) {
      a1[i] = *(const bf16x8*)&Us[(wy * 64 + i * 16 + lr) * 256 + colOff];
      a2[i] = *(const bf16x8*)&Fws[(wy * 64 + i * 16 + lr) * 256 + colOff];
    }
#pragma unroll
    for (int j = 0; j < 2; ++j) bbf[j] = *(const bf16x8*)&bs[(wx * 32 + j * 16 + lr) * 32 + bOff];
#pragma unroll
    for (int i = 0; i < 4; ++i)
#pragma unroll
      for (int j = 0; j < 2; ++j) {
        accs[i][j] = __builtin_amdgcn_mfma_f32_16x16x32_bf16(a1[i], bbf[j], accs[i][j], 0, 0, 0);
        accg[i][j] = __builtin_amdgcn_mfma_f32_16x16x32_bf16(a2[i], bbf[j], accg[i][j], 0, 0, 0);
      }
    if (kt == 7) {
#pragma unroll
      for (int i = 0; i < 4; ++i)
#pragma unroll
        for (int r = 0; r < 4; ++r) {
          const int row = wy * 64 + i * 16 + lq * 4 + r;
          const int y = yt * 128 + row;
          const float sv = si[i][r];
          float ns = 0.f;
#pragma unroll
          for (int j = 0; j < 2; ++j) {
            const float av = __expf(accs[i][j][r]) * sv;
            ns += av * accg[i][j][r];
            if (y < Y_) {
              const int l = lt * 128 + wx * 32 + j * 16 + lr;
              alpha[((size_t)b * Y_ + y) * L_ + l] = av;
            }
          }
#pragma unroll
          for (int off = 1; off < 16; off <<= 1) ns += __shfl_xor(ns, off);
          nsA[i][r] += ns;
        }
    }
  }
  // ---- combine ns across wx, write yhat ----
  __syncthreads();
  float* red2 = (float*)Bs;
#pragma unroll
  for (int i = 0; i < 4; ++i)
#pragma unroll
    for (int r = 0; r < 4; ++r)
      if (lr == 0) red2[(wy * 64 + i * 16 + lq * 4 + r) * 4 + wx] = nsA[i][r];
  __syncthreads();
  if (tid < 128) {
    const int y = yt * 128 + tid;
    if (y < Y_) {
      yhat[(size_t)b * Y_ + y] = Fb[y] + red2[tid * 4] + red2[tid * 4 + 1] +
                                 red2[tid * 4 + 2] + red2[tid * 4 + 3];
    }
  }
}

// ---------------- loss ------------------------------------------------------
__global__ __launch_bounds__(256) void loss_part_kernel(const float* __restrict__ yhat,
                                                        const float* __restrict__ target,
                                                        float* __restrict__ part) {
  __shared__ float red[256];
  float s = 0.f;
  for (int i = blockIdx.x * 256 + threadIdx.x; i < B_ * Y_; i += gridDim.x * 256) {
    float yh = yhat[i], t = target[i];
    s += fmaxf(yh, 0.f) - yh * t + log1pf(expf(-fabsf(yh)));
  }
  red[threadIdx.x] = s;
  __syncthreads();
  for (int o = 128; o > 0; o >>= 1) {
    if (threadIdx.x < o) red[threadIdx.x] += red[threadIdx.x + o];
    __syncthreads();
  }
  if (threadIdx.x == 0) part[blockIdx.x] = red[0];
}

__global__ __launch_bounds__(128) void loss_final_kernel(const float* __restrict__ part,
                                                         float* __restrict__ loss) {
  __shared__ float red[128];
  red[threadIdx.x] = part[threadIdx.x];
  __syncthreads();
  for (int o = 64; o > 0; o >>= 1) {
    if (threadIdx.x < o) red[threadIdx.x] += red[threadIdx.x + o];
    __syncthreads();
  }
  if (threadIdx.x == 0) loss[0] = red[0] * (1.f / (float)(B_ * Y_));
}

extern "C" void kernel_launch(void* const* d_in, const int* in_sizes, int n_in,
                              void* d_out, int out_size, void* d_ws, size_t ws_size,
                              hipStream_t stream) {
  const int* x = (const int*)d_in[0];
  const float* target = (const float*)d_in[1];
  const float* embedW = (const float*)d_in[2];
  const float* convw = (const float*)d_in[3];
  const float* convb = (const float*)d_in[4];
  const float* Uw = (const float*)d_in[5];
  const float* Fww = (const float*)d_in[6];
  const float* Fb = (const float*)d_in[7];

  float* out = (float*)d_out;
  float* yhat = out;                 // [B*Y] = 71368
  float* loss = out + 71368;         // [1]
  float* alpha = out + 71369;        // [B*Y*L]

  char* w = (char*)d_ws;
  size_t off = 0;
  auto alloc = [&](size_t bytes) -> void* {
    void* p = w + off;
    off += (bytes + 255) & ~(size_t)255;
    return p;
  };
  unsigned short* im2col = (unsigned short*)alloc((size_t)MC * KC * 2);  // 30.4 MB
  unsigned short* wconv = (unsigned short*)alloc((size_t)F_ * KC * 2);   // 0.5 MB
  unsigned short* Ub = (unsigned short*)alloc((size_t)YP * F_ * 2);      // 4.6 MB
  unsigned short* Fwb = (unsigned short*)alloc((size_t)YP * F_ * 2);     // 4.6 MB
  unsigned short* hb = (unsigned short*)alloc((size_t)MC * F_ * 2);      // 8.4 MB
  float* lpart = (float*)alloc(128 * 4);

  im2col_kernel<<<(MC * (KC / 4) + 255) / 256, 256, 0, stream>>>(x, embedW, im2col);
  wpack_kernel<<<(F_ * KC + 255) / 256, 256, 0, stream>>>(convw, wconv);
  ufpack_kernel<<<(2 * YP * F_ + 255) / 256, 256, 0, stream>>>(Uw, Fww, Ub, Fwb);
  conv_gemm<<<dim3(128, 2), 256, 0, stream>>>(im2col, wconv, convb, hb);
  attn_fused<<<dim3(70, 8), 512, 0, stream>>>(Ub, Fwb, hb, Fb, alpha, yhat);
  loss_part_kernel<<<128, 256, 0, stream>>>(yhat, target, lpart);
  loss_final_kernel<<<1, 128, 0, stream>>>(lpart, loss);
}